// Round 5
// baseline (874.596 us; speedup 1.0000x reference)
//
#include <hip/hip_runtime.h>

// AdaptiveGraphConvolution on MI355X (gfx950)
// out = sum_l m_l * (A_l @ x) @ W_l + bias
//
// R5: R4's atomic-free bucket build kept; fused kernel restructured for
// latency hiding: 1024-thread blocks (16 waves), ONE WAVE PER ROW (50000
// row-waves, R2-proven parallelism). Stage phase prefetches col/val into the
// LDS counting-sort records (off the serial chain); per-edge chain is just
// LDS-read -> xb bf16 gather -> FMA. GEMM: 16 waves share LDS-staged m*W.
// Zero global atomics, out written once. ~30.7 MB workspace.

constexpr int N = 50000;
constexpr int E = 800000;
constexpr int D = 128;
constexpr int L = 4;
constexpr int BSH = 4;            // 16 rows per bucket
constexpr int NB = N >> BSH;      // 3125 buckets (exact)
constexpr int NCHK = 100;         // chunks per graph
constexpr int CHUNK = E / NCHK;   // 8000 edges per chunk (exact)
constexpr int CAP = 1024;         // staged edges per bucket per graph (avg 256)

// ---------------------------------------------------------------------------
// 0) x f32 -> bf16 (RNE), packed 2/uint.
// ---------------------------------------------------------------------------
__device__ inline unsigned bf16rne(unsigned u) {
    return (u + 0x7FFFu + ((u >> 16) & 1u)) >> 16;
}
__global__ __launch_bounds__(256) void cvt_x_kernel(
    const float* __restrict__ x, unsigned* __restrict__ xb)
{
    int i = blockIdx.x * 256 + threadIdx.x;
    float2 v = reinterpret_cast<const float2*>(x)[i];
    xb[i] = bf16rne(__float_as_uint(v.x)) | (bf16rne(__float_as_uint(v.y)) << 16);
}

// ---------------------------------------------------------------------------
// 1) Per-chunk bucket histogram (LDS only).
// ---------------------------------------------------------------------------
__global__ __launch_bounds__(256) void bucket_hist_kernel(
    const int* __restrict__ edge_rows, unsigned* __restrict__ pcnt)
{
    __shared__ int cnt[NB];
    const int blk = blockIdx.x, g = blockIdx.y, tid = threadIdx.x;
    for (int i = tid; i < NB; i += 256) cnt[i] = 0;
    __syncthreads();
    const int* rows = edge_rows + (size_t)g * E + (size_t)blk * CHUNK;
    for (int i = tid; i < CHUNK; i += 256)
        atomicAdd(&cnt[rows[i] >> BSH], 1);
    __syncthreads();
    unsigned* outp = pcnt + ((size_t)g * NCHK + blk) * NB;
    for (int i = tid; i < NB; i += 256) outp[i] = cnt[i];
}

// ---------------------------------------------------------------------------
// 2a) Column pass: pcnt -> per-chunk offsets; bucket totals -> bstart.
// ---------------------------------------------------------------------------
__global__ __launch_bounds__(256) void scan1_kernel(
    unsigned* __restrict__ pcnt, int* __restrict__ bstart)
{
    const int b = blockIdx.x * 256 + threadIdx.x;
    const int g = blockIdx.y;
    if (b >= NB) return;
    unsigned run = 0;
    unsigned* p = pcnt + (size_t)g * NCHK * NB + b;
    for (int blk = 0; blk < NCHK; ++blk) {
        unsigned v = p[(size_t)blk * NB];
        p[(size_t)blk * NB] = run;
        run += v;
    }
    bstart[(size_t)g * (NB + 1) + b] = (int)run;
}

// ---------------------------------------------------------------------------
// 2b) Per-graph exclusive scan of bucket totals.
// ---------------------------------------------------------------------------
__global__ __launch_bounds__(1024) void scan2_kernel(int* __restrict__ bstart)
{
    __shared__ int sums[1024];
    int* bs = bstart + (size_t)blockIdx.x * (NB + 1);
    const int t = threadIdx.x;
    int tv[4];
    int s = 0;
#pragma unroll
    for (int i = 0; i < 4; ++i) {
        int idx = t * 4 + i;
        tv[i] = (idx < NB) ? bs[idx] : 0;
        s += tv[i];
    }
    sums[t] = s;
    __syncthreads();
    for (int off = 1; off < 1024; off <<= 1) {
        int v = (t >= off) ? sums[t - off] : 0;
        __syncthreads();
        sums[t] += v;
        __syncthreads();
    }
    int ex = (t == 0) ? 0 : sums[t - 1];
#pragma unroll
    for (int i = 0; i < 4; ++i) {
        int idx = t * 4 + i;
        if (idx < NB) { bs[idx] = ex; ex += tv[i]; }
    }
    if (t == 0) bs[NB] = E;
}

// ---------------------------------------------------------------------------
// 3) Fill: bucket-sorted packed indices sidx = e | rowloc<<28.
// ---------------------------------------------------------------------------
__global__ __launch_bounds__(256) void fill_kernel(
    const int* __restrict__ edge_rows,
    const unsigned* __restrict__ pcnt,
    const int* __restrict__ bstart,
    unsigned* __restrict__ sidx)
{
    __shared__ int base[NB];
    __shared__ int cur[NB];
    const int blk = blockIdx.x, g = blockIdx.y, tid = threadIdx.x;
    const unsigned* pc = pcnt + ((size_t)g * NCHK + blk) * NB;
    const int* bs = bstart + (size_t)g * (NB + 1);
    for (int i = tid; i < NB; i += 256) {
        base[i] = bs[i] + (int)pc[i];
        cur[i] = 0;
    }
    __syncthreads();
    const int* rows = edge_rows + (size_t)g * E + (size_t)blk * CHUNK;
    unsigned* sg = sidx + (size_t)g * E;
    for (int i = tid; i < CHUNK; i += 256) {
        int r = rows[i];
        int b = r >> BSH;
        int rank = atomicAdd(&cur[b], 1);
        sg[base[b] + rank] = (unsigned)(blk * CHUNK + i) | ((unsigned)(r & 15) << 28);
    }
}

// ---------------------------------------------------------------------------
// 4) Fused SpMM + projection. Block = 1024 threads = 16 waves = one bucket;
//    ONE WAVE PER ROW. Per graph: stage (prefetch col/val, pack int2) ->
//    LDS counting sort by row -> per-wave register gather (bf16 x) ->
//    accL -> GEMM via LDS-staged m*W (bias folded). One out write.
// ---------------------------------------------------------------------------
__global__ __launch_bounds__(1024) void fused_kernel(
    const unsigned* __restrict__ xb,      // [N][64] packed bf16 pairs
    const unsigned* __restrict__ sidx,    // [L][E]
    const int* __restrict__ bstart,       // [L][NB+1]
    const int* __restrict__ edge_cols,    // [L][E]
    const float* __restrict__ edge_vals,  // [L][E]
    const float* __restrict__ W,          // [L][D][D]
    const float* __restrict__ mix,        // [L]
    const float* __restrict__ bias,       // [D]
    float* __restrict__ out)              // [N][D]
{
    // union: {su int2[CAP] 8K | ssorted int2[CAP] 8K}  <->  wc f32[32][128] 16K
    __shared__ __align__(16) char smem[16384];
    int2* su      = (int2*)smem;
    int2* ssorted = (int2*)(smem + 8192);
    float* wc     = (float*)smem;
    __shared__ float accL[16][D];   // 8 KB
    __shared__ int rc[17];
    __shared__ int rcur[16];

    const int b = blockIdx.x, tid = threadIdx.x;
    const int lane = tid & 63, wave = tid >> 6;   // wave = local row 0..15
    const int f0 = 2 * lane;

    float2 oa = *reinterpret_cast<const float2*>(bias + f0);

    for (int l = 0; l < L; ++l) {
        const unsigned* sg = sidx + (size_t)l * E;
        const int* cols_g = edge_cols + (size_t)l * E;
        const float* vals_g = edge_vals + (size_t)l * E;
        const int beg = bstart[l * (NB + 1) + b];
        const int end = bstart[l * (NB + 1) + b + 1];
        const int cnt = end - beg;
        const int scnt = cnt < CAP ? cnt : CAP;

        if (tid < 17) rc[tid] = 0;
        __syncthreads();
        // stage: prefetch col/val (thread-parallel; off the serial chain)
        for (int i = tid; i < scnt; i += 1024) {
            unsigned v = sg[beg + i];
            int e = (int)(v & 0x0FFFFFFFu);
            int rl = (int)(v >> 28);
            su[i] = make_int2((cols_g[e] << 4) | rl, __float_as_int(vals_g[e]));
            atomicAdd(&rc[rl + 1], 1);
        }
        __syncthreads();
        if (tid == 0) {
            int run = 0;
#pragma unroll
            for (int r = 1; r <= 16; ++r) {
                run += rc[r];
                rc[r] = run;
                rcur[r - 1] = (r == 1) ? 0 : rc[r - 1];
            }
        }
        __syncthreads();
        for (int i = tid; i < scnt; i += 1024) {
            int2 v = su[i];
            int p = atomicAdd(&rcur[v.x & 15], 1);
            ssorted[p] = v;
        }
        __syncthreads();

        // per-wave gather: wave handles row (b*16 + wave)
        float2 g2 = make_float2(0.f, 0.f);
        {
            const int s0 = rc[wave], s1 = rc[wave + 1];
            for (int j = s0; j < s1; ++j) {
                int2 p = ssorted[j];                  // LDS b64 broadcast
                float val = __int_as_float(p.y);
                int c = p.x >> 4;
                unsigned xv = xb[(size_t)c * 64 + lane];
                g2.x = fmaf(val, __uint_as_float(xv << 16), g2.x);
                g2.y = fmaf(val, __uint_as_float(xv & 0xFFFF0000u), g2.y);
            }
        }
        // overflow net (cnt > CAP: statistically never)
        for (int j = beg + scnt; j < end; ++j) {
            unsigned v = sg[j];
            if ((int)(v >> 28) == wave) {
                int e = (int)(v & 0x0FFFFFFFu);
                float val = vals_g[e];
                unsigned xv = xb[(size_t)cols_g[e] * 64 + lane];
                g2.x = fmaf(val, __uint_as_float(xv << 16), g2.x);
                g2.y = fmaf(val, __uint_as_float(xv & 0xFFFF0000u), g2.y);
            }
        }
        *reinterpret_cast<float2*>(&accL[wave][f0]) = g2;
        __syncthreads();   // accL ready; su/ssorted dead -> wc may overwrite

        // GEMM: oa += accL[wave] @ (m * W_l)
        const float m = mix[l];
        const float4* wsrc = reinterpret_cast<const float4*>(W + (size_t)l * D * D);
        for (int kc = 0; kc < 4; ++kc) {
            {
                float4 t = wsrc[kc * 1024 + tid];
                reinterpret_cast<float4*>(wc)[tid] =
                    make_float4(m * t.x, m * t.y, m * t.z, m * t.w);
            }
            __syncthreads();
#pragma unroll
            for (int d4 = 0; d4 < 8; ++d4) {
                float4 av = *reinterpret_cast<const float4*>(&accL[wave][kc * 32 + d4 * 4]);
#pragma unroll
                for (int jj = 0; jj < 4; ++jj) {
                    float2 wv =
                        reinterpret_cast<const float2*>(wc)[(d4 * 4 + jj) * 64 + lane];
                    float s = (jj == 0) ? av.x
                            : (jj == 1) ? av.y
                            : (jj == 2) ? av.z
                                        : av.w;
                    oa.x = fmaf(s, wv.x, oa.x);
                    oa.y = fmaf(s, wv.y, oa.y);
                }
            }
            __syncthreads();
        }
    }

    const int row = b * 16 + wave;
    *reinterpret_cast<float2*>(out + (size_t)row * D + f0) = oa;
}

extern "C" void kernel_launch(void* const* d_in, const int* in_sizes, int n_in,
                              void* d_out, int out_size, void* d_ws, size_t ws_size,
                              hipStream_t stream)
{
    const float* x         = (const float*)d_in[0];
    const int*   edge_rows = (const int*)d_in[1];
    const int*   edge_cols = (const int*)d_in[2];
    const float* edge_vals = (const float*)d_in[3];
    const float* W         = (const float*)d_in[4];
    const float* mix       = (const float*)d_in[5];
    const float* bias      = (const float*)d_in[6];
    float* out = (float*)d_out;

    // Workspace (~30.7 MB): sidx [L][E] uint | pcnt [L][NCHK][NB] | bstart | xb
    unsigned* sidx   = (unsigned*)d_ws;
    unsigned* pcnt   = sidx + (size_t)L * E;
    int*      bstart = (int*)(pcnt + (size_t)L * NCHK * NB);
    unsigned* xb     = (unsigned*)(bstart + (size_t)L * (NB + 1));

    cvt_x_kernel<<<(N * D / 2) / 256, 256, 0, stream>>>(x, xb);
    bucket_hist_kernel<<<dim3(NCHK, L), 256, 0, stream>>>(edge_rows, pcnt);
    scan1_kernel<<<dim3((NB + 255) / 256, L), 256, 0, stream>>>(pcnt, bstart);
    scan2_kernel<<<L, 1024, 0, stream>>>(bstart);
    fill_kernel<<<dim3(NCHK, L), 256, 0, stream>>>(edge_rows, pcnt, bstart, sidx);
    fused_kernel<<<NB, 1024, 0, stream>>>(xb, sidx, bstart, edge_cols, edge_vals,
                                          W, mix, bias, out);
}

// Round 6
// 504.018 us; speedup vs baseline: 1.7352x; 1.7352x over previous
//
#include <hip/hip_runtime.h>

// AdaptiveGraphConvolution on MI355X (gfx950)
// out = sum_l m_l * (A_l @ x) @ W_l + bias
//
// R6: atomic-free two-level sort to FULL row granularity (bucket sort +
// per-bucket LDS counting sort -> CSR rowptr), then a BARRIER-FREE gather:
// one wave per row, 64 edges' {col,val} pre-loaded in parallel and
// broadcast via shfl, so the per-edge critical path is one 4B/lane xb read.
// y kept as packed bf16; R2-style GEMM-accumulate per graph.
// 14 dispatches, ~44.3 MB workspace, zero global atomics.

constexpr int N = 50000;
constexpr int E = 800000;
constexpr int D = 128;
constexpr int L = 4;
constexpr int BSH = 4;            // 16 rows per bucket
constexpr int NB = N >> BSH;      // 3125 buckets (exact)
constexpr int NCHK = 100;         // chunks per graph
constexpr int CHUNK = E / NCHK;   // 8000 edges per chunk
constexpr int CAP = 1024;         // max sortable bucket size (actual max ~330)

__device__ inline unsigned bf16rne(unsigned u) {
    return (u + 0x7FFFu + ((u >> 16) & 1u)) >> 16;
}

// ---------------------------------------------------------------------------
// 0) x f32 -> packed bf16 pairs. xb[r*64+j] = {x[r][2j] lo, x[r][2j+1] hi}
// ---------------------------------------------------------------------------
__global__ __launch_bounds__(256) void cvt_x_kernel(
    const float* __restrict__ x, unsigned* __restrict__ xb)
{
    int i = blockIdx.x * 256 + threadIdx.x;
    float2 v = reinterpret_cast<const float2*>(x)[i];
    xb[i] = bf16rne(__float_as_uint(v.x)) | (bf16rne(__float_as_uint(v.y)) << 16);
}

// ---------------------------------------------------------------------------
// 1) Per-chunk bucket histogram (LDS only).
// ---------------------------------------------------------------------------
__global__ __launch_bounds__(256) void bucket_hist_kernel(
    const int* __restrict__ edge_rows, unsigned* __restrict__ pcnt)
{
    __shared__ int cnt[NB];
    const int blk = blockIdx.x, g = blockIdx.y, tid = threadIdx.x;
    for (int i = tid; i < NB; i += 256) cnt[i] = 0;
    __syncthreads();
    const int* rows = edge_rows + (size_t)g * E + (size_t)blk * CHUNK;
    for (int i = tid; i < CHUNK; i += 256)
        atomicAdd(&cnt[rows[i] >> BSH], 1);
    __syncthreads();
    unsigned* outp = pcnt + ((size_t)g * NCHK + blk) * NB;
    for (int i = tid; i < NB; i += 256) outp[i] = cnt[i];
}

// ---------------------------------------------------------------------------
// 2a) Column pass: pcnt -> per-chunk offsets; bucket totals -> bstart.
// ---------------------------------------------------------------------------
__global__ __launch_bounds__(256) void scan1_kernel(
    unsigned* __restrict__ pcnt, int* __restrict__ bstart)
{
    const int b = blockIdx.x * 256 + threadIdx.x;
    const int g = blockIdx.y;
    if (b >= NB) return;
    unsigned run = 0;
    unsigned* p = pcnt + (size_t)g * NCHK * NB + b;
    for (int blk = 0; blk < NCHK; ++blk) {
        unsigned v = p[(size_t)blk * NB];
        p[(size_t)blk * NB] = run;
        run += v;
    }
    bstart[(size_t)g * (NB + 1) + b] = (int)run;
}

// ---------------------------------------------------------------------------
// 2b) Per-graph exclusive scan of bucket totals.
// ---------------------------------------------------------------------------
__global__ __launch_bounds__(1024) void scan2_kernel(int* __restrict__ bstart)
{
    __shared__ int sums[1024];
    int* bs = bstart + (size_t)blockIdx.x * (NB + 1);
    const int t = threadIdx.x;
    int tv[4];
    int s = 0;
#pragma unroll
    for (int i = 0; i < 4; ++i) {
        int idx = t * 4 + i;
        tv[i] = (idx < NB) ? bs[idx] : 0;
        s += tv[i];
    }
    sums[t] = s;
    __syncthreads();
    for (int off = 1; off < 1024; off <<= 1) {
        int v = (t >= off) ? sums[t - off] : 0;
        __syncthreads();
        sums[t] += v;
        __syncthreads();
    }
    int ex = (t == 0) ? 0 : sums[t - 1];
#pragma unroll
    for (int i = 0; i < 4; ++i) {
        int idx = t * 4 + i;
        if (idx < NB) { bs[idx] = ex; ex += tv[i]; }
    }
    if (t == 0) bs[NB] = E;
}

// ---------------------------------------------------------------------------
// 3) Fill: bucket-sorted packed indices sidx = e | rowloc<<28.
// ---------------------------------------------------------------------------
__global__ __launch_bounds__(256) void fill_kernel(
    const int* __restrict__ edge_rows,
    const unsigned* __restrict__ pcnt,
    const int* __restrict__ bstart,
    unsigned* __restrict__ sidx)
{
    __shared__ int base[NB];
    __shared__ int cur[NB];
    const int blk = blockIdx.x, g = blockIdx.y, tid = threadIdx.x;
    const unsigned* pc = pcnt + ((size_t)g * NCHK + blk) * NB;
    const int* bs = bstart + (size_t)g * (NB + 1);
    for (int i = tid; i < NB; i += 256) {
        base[i] = bs[i] + (int)pc[i];
        cur[i] = 0;
    }
    __syncthreads();
    const int* rows = edge_rows + (size_t)g * E + (size_t)blk * CHUNK;
    unsigned* sg = sidx + (size_t)g * E;
    for (int i = tid; i < CHUNK; i += 256) {
        int r = rows[i];
        int b = r >> BSH;
        int rank = atomicAdd(&cur[b], 1);
        sg[base[b] + rank] = (unsigned)(blk * CHUNK + i) | ((unsigned)(r & 15) << 28);
    }
}

// ---------------------------------------------------------------------------
// 4) sort2: per-bucket LDS counting sort by rowloc (in place) + CSR rowptr.
//    Buckets > CAP (never for this data) left unsorted, rows flagged.
// ---------------------------------------------------------------------------
__global__ __launch_bounds__(256) void sort2_kernel(
    unsigned* __restrict__ sidx,
    const int* __restrict__ bstart,
    int* __restrict__ rowptr)
{
    __shared__ unsigned su[CAP], ss[CAP];
    __shared__ int rc[17], rcur[16];
    const int b = blockIdx.x, g = blockIdx.y, tid = threadIdx.x;
    const int beg = bstart[(size_t)g * (NB + 1) + b];
    const int end = bstart[(size_t)g * (NB + 1) + b + 1];
    const int cnt = end - beg;
    unsigned* sg = sidx + (size_t)g * E;
    int* rp = rowptr + (size_t)g * (N + 1);
    if (b == 0 && tid == 0) rp[N] = E;
    if (cnt > CAP) {   // correctness net; statistically impossible here
        if (tid < 16) rp[b * 16 + tid] = (int)(0x80000000u | (unsigned)beg);
        return;
    }
    if (tid < 17) rc[tid] = 0;
    __syncthreads();
    for (int i = tid; i < cnt; i += 256) {
        unsigned v = sg[beg + i];
        su[i] = v;
        atomicAdd(&rc[(v >> 28) + 1], 1);
    }
    __syncthreads();
    if (tid == 0) {
        int run = 0;
#pragma unroll
        for (int r = 1; r <= 16; ++r) { run += rc[r]; rc[r] = run; }
    }
    __syncthreads();
    if (tid < 16) {
        rcur[tid] = rc[tid];
        rp[b * 16 + tid] = beg + rc[tid];
    }
    __syncthreads();
    for (int i = tid; i < cnt; i += 256) {
        unsigned v = su[i];
        int p = atomicAdd(&rcur[v >> 28], 1);
        ss[p] = v;
    }
    __syncthreads();
    for (int i = tid; i < cnt; i += 256) sg[beg + i] = ss[i];
}

// ---------------------------------------------------------------------------
// 5) Gather: ONE WAVE PER ROW, barrier-free. Wave pre-loads 64 edges'
//    {col,val} in parallel (coalesced sidx + parallel random 4B loads),
//    then per edge: shfl-broadcast -> xb row read -> fma. y packed bf16.
// ---------------------------------------------------------------------------
__global__ __launch_bounds__(256) void gather_kernel(
    const unsigned* __restrict__ xb,      // [N][64]
    const unsigned* __restrict__ sidx_g,  // [E]
    const int* __restrict__ rowptr_g,     // [N+1]
    const int* __restrict__ bstart_g,     // [NB+1]
    const int* __restrict__ cols_g,
    const float* __restrict__ vals_g,
    unsigned* __restrict__ y)             // [N][64]
{
    const int w = (blockIdx.x * 256 + threadIdx.x) >> 6;   // row
    const int lane = threadIdx.x & 63;

    float2 acc = make_float2(0.f, 0.f);
    const int rpv = rowptr_g[w];
    if (rpv >= 0) {
        const int end = rowptr_g[w + 1] & 0x7FFFFFFF;
        for (int base = rpv; base < end; base += 64) {
            const int m = end - base;
            const int kmax = m < 64 ? m : 64;
            int idx = base + (lane < m ? lane : 0);
            unsigned ep = sidx_g[idx];
            int e = (int)(ep & 0x0FFFFFFFu);
            int c = cols_g[e];          // thread-parallel random 4B loads
            float v = vals_g[e];
            for (int k = 0; k < kmax; ++k) {
                int ck = __shfl(c, k);
                float vk = __shfl(v, k);
                unsigned xv = xb[(size_t)ck * 64 + lane];
                acc.x = fmaf(vk, __uint_as_float(xv << 16), acc.x);
                acc.y = fmaf(vk, __uint_as_float(xv & 0xFFFF0000u), acc.y);
            }
        }
    } else {
        // overflow-bucket fallback (never taken for this dataset)
        const int b = w >> BSH, rl = w & 15;
        const int beg = bstart_g[b], bend = bstart_g[b + 1];
        for (int j = beg; j < bend; ++j) {
            unsigned ep = sidx_g[j];
            if ((int)(ep >> 28) == rl) {
                int e = (int)(ep & 0x0FFFFFFFu);
                float v = vals_g[e];
                unsigned xv = xb[(size_t)cols_g[e] * 64 + lane];
                acc.x = fmaf(v, __uint_as_float(xv << 16), acc.x);
                acc.y = fmaf(v, __uint_as_float(xv & 0xFFFF0000u), acc.y);
            }
        }
    }
    y[(size_t)w * 64 + lane] = bf16rne(__float_as_uint(acc.x)) |
                               (bf16rne(__float_as_uint(acc.y)) << 16);
}

// ---------------------------------------------------------------------------
// 6) GEMM-accumulate: out[n][f] (+)= sum_d y[n][d] * (m*W[d][f]) (+bias on l==0)
//    y is packed bf16; unpacked to f32 during LDS staging. R2 structure.
// ---------------------------------------------------------------------------
__global__ __launch_bounds__(256) void gemm_acc_kernel(
    const unsigned* __restrict__ y,   // [N][64] bf16 pairs
    const float* __restrict__ W,
    const float* __restrict__ mix,
    const float* __restrict__ bias,
    float* __restrict__ out,
    int init)
{
    __shared__ float lds_w[64 * D];   // 32 KB
    __shared__ float lds_y[32][64];   // 8 KB

    const int tid = threadIdx.x;
    const int lane = tid & 63;
    const int wave = tid >> 6;
    const int r0 = blockIdx.x * 32;
    const int f0 = 2 * lane;
    const float m = mix[0];
    const int wr = r0 + wave * 8;

    float2 acc[8];
#pragma unroll
    for (int r = 0; r < 8; ++r) {
        int row = wr + r;
        if (init) {
            acc[r].x = bias[f0];
            acc[r].y = bias[f0 + 1];
        } else if (row < N) {
            acc[r] = *reinterpret_cast<const float2*>(out + (size_t)row * D + f0);
        } else {
            acc[r] = make_float2(0.f, 0.f);
        }
    }

    for (int kc = 0; kc < 2; ++kc) {
        {   // stage W chunk [64][128] scaled by m
            const float4* wsrc = reinterpret_cast<const float4*>(W + kc * 64 * D);
            float4* wdst = reinterpret_cast<float4*>(lds_w);
#pragma unroll
            for (int i = 0; i < 8; ++i) {
                int idx = i * 256 + tid;
                float4 wv = wsrc[idx];
                wdst[idx] = make_float4(m * wv.x, m * wv.y, m * wv.z, m * wv.w);
            }
        }
        {   // stage y tile [32 rows][64 d] from packed bf16 (uint4 loads)
            int rl = tid >> 3;
            int j = (tid & 7) * 4;        // u32 offset within 32-u32 chunk
            int row = r0 + rl;
            uint4 p = make_uint4(0, 0, 0, 0);
            if (row < N)
                p = *reinterpret_cast<const uint4*>(y + (size_t)row * 64 + kc * 32 + j);
            float* dst = &lds_y[rl][j * 2];
            dst[0] = __uint_as_float(p.x << 16);
            dst[1] = __uint_as_float(p.x & 0xFFFF0000u);
            dst[2] = __uint_as_float(p.y << 16);
            dst[3] = __uint_as_float(p.y & 0xFFFF0000u);
            dst[4] = __uint_as_float(p.z << 16);
            dst[5] = __uint_as_float(p.z & 0xFFFF0000u);
            dst[6] = __uint_as_float(p.w << 16);
            dst[7] = __uint_as_float(p.w & 0xFFFF0000u);
        }
        __syncthreads();

        const int wrow = wave * 8;
#pragma unroll
        for (int d4 = 0; d4 < 64; d4 += 4) {
            float4 yv[8];
#pragma unroll
            for (int r = 0; r < 8; ++r)
                yv[r] = *reinterpret_cast<const float4*>(&lds_y[wrow + r][d4]);
#pragma unroll
            for (int j = 0; j < 4; ++j) {
                float2 wv = *reinterpret_cast<const float2*>(&lds_w[(d4 + j) * D + f0]);
#pragma unroll
                for (int r = 0; r < 8; ++r) {
                    float ys = (j == 0) ? yv[r].x
                             : (j == 1) ? yv[r].y
                             : (j == 2) ? yv[r].z
                                        : yv[r].w;
                    acc[r].x = fmaf(ys, wv.x, acc[r].x);
                    acc[r].y = fmaf(ys, wv.y, acc[r].y);
                }
            }
        }
        __syncthreads();
    }

#pragma unroll
    for (int r = 0; r < 8; ++r) {
        int row = wr + r;
        if (row < N)
            *reinterpret_cast<float2*>(out + (size_t)row * D + f0) = acc[r];
    }
}

extern "C" void kernel_launch(void* const* d_in, const int* in_sizes, int n_in,
                              void* d_out, int out_size, void* d_ws, size_t ws_size,
                              hipStream_t stream)
{
    const float* x         = (const float*)d_in[0];
    const int*   edge_rows = (const int*)d_in[1];
    const int*   edge_cols = (const int*)d_in[2];
    const float* edge_vals = (const float*)d_in[3];
    const float* W         = (const float*)d_in[4];
    const float* mix       = (const float*)d_in[5];
    const float* bias      = (const float*)d_in[6];
    float* out = (float*)d_out;

    // Workspace (~44.3 MB):
    // sidx [L][E] u32 | pcnt [L][NCHK][NB] | bstart [L][NB+1] |
    // rowptr [L][N+1] | xb [N][64] | y [N][64]
    unsigned* sidx   = (unsigned*)d_ws;
    unsigned* pcnt   = sidx + (size_t)L * E;
    int*      bstart = (int*)(pcnt + (size_t)L * NCHK * NB);
    int*      rowptr = bstart + (size_t)L * (NB + 1);
    unsigned* xb     = (unsigned*)(rowptr + (size_t)L * (N + 1));
    unsigned* y      = xb + (size_t)N * 64;

    cvt_x_kernel<<<(N * D / 2) / 256, 256, 0, stream>>>(x, xb);
    bucket_hist_kernel<<<dim3(NCHK, L), 256, 0, stream>>>(edge_rows, pcnt);
    scan1_kernel<<<dim3((NB + 255) / 256, L), 256, 0, stream>>>(pcnt, bstart);
    scan2_kernel<<<L, 1024, 0, stream>>>(bstart);
    fill_kernel<<<dim3(NCHK, L), 256, 0, stream>>>(edge_rows, pcnt, bstart, sidx);
    sort2_kernel<<<dim3(NB, L), 256, 0, stream>>>(sidx, bstart, rowptr);

    for (int l = 0; l < L; ++l) {
        gather_kernel<<<(N * 64) / 256, 256, 0, stream>>>(
            xb,
            sidx + (size_t)l * E,
            rowptr + (size_t)l * (N + 1),
            bstart + (size_t)l * (NB + 1),
            edge_cols + (size_t)l * E,
            edge_vals + (size_t)l * E,
            y);
        gemm_acc_kernel<<<(N + 31) / 32, 256, 0, stream>>>(
            y, W + (size_t)l * D * D, mix + l, bias, out, l == 0 ? 1 : 0);
    }
}